// Round 6
// baseline (666.430 us; speedup 1.0000x reference)
//
#include <hip/hip_runtime.h>

typedef unsigned short ushort_t;
typedef __attribute__((ext_vector_type(8))) short short8;
typedef __attribute__((ext_vector_type(4))) float f32x4;

#define Bb 2
#define Ss 2048
#define HID 2048
#define NH 16
#define NKV 4
#define Dd 128
constexpr float EPS_ = 1e-6f;
constexpr float THETA_ = 1000000.0f;
constexpr float SCALE_ = 0.08838834764831845f; // 128^-0.5
constexpr float C2_ = 0.12753785f;             // SCALE * log2(e)

__device__ __forceinline__ ushort_t f2bf(float x) {
  union { float f; unsigned u; } v; v.f = x;
  unsigned r = (v.u + 0x7fffu + ((v.u >> 16) & 1u)) >> 16;
  return (ushort_t)r;
}
__device__ __forceinline__ float bf2f(ushort_t u) {
  union { unsigned u; float f; } v; v.u = ((unsigned)u) << 16;
  return v.f;
}

typedef const __attribute__((address_space(1))) void* gas1_t;
typedef __attribute__((address_space(3))) void* las3_t;
__device__ __forceinline__ void gload_lds16(const void* g, void* l) {
  __builtin_amdgcn_global_load_lds((gas1_t)g, (las3_t)l, 16, 0, 0);
}

__device__ __forceinline__ void store_out(float* p, float v) { *p = v; }
__device__ __forceinline__ void store_out(ushort_t* p, float v) { *p = f2bf(v); }

// ---------------- fp32 -> bf16 straight convert ----------------
__global__ __launch_bounds__(256) void convert_f32_bf16(
    const float* __restrict__ src, ushort_t* __restrict__ dst, long n) {
  long i = ((long)blockIdx.x * 256 + threadIdx.x) * 4;
  if (i + 3 < n) {
    float4 v = *(const float4*)(src + i);
    ushort_t o0 = f2bf(v.x), o1 = f2bf(v.y), o2 = f2bf(v.z), o3 = f2bf(v.w);
    ushort_t* d = dst + i;
    d[0] = o0; d[1] = o1; d[2] = o2; d[3] = o3;
  }
}

// ---------------- fp32 (R x C) -> bf16 transposed (C x R) ----------------
__global__ __launch_bounds__(256) void transpose_f32_bf16(
    const float* __restrict__ src, ushort_t* __restrict__ dst, int R, int C) {
  __shared__ float tile[32][33];
  int c0 = blockIdx.x * 32, r0 = blockIdx.y * 32;
  int tx = threadIdx.x & 31, ty = threadIdx.x >> 5; // ty 0..7
#pragma unroll
  for (int j = 0; j < 4; j++)
    tile[ty + j * 8][tx] = src[(long)(r0 + ty + j * 8) * C + c0 + tx];
  __syncthreads();
#pragma unroll
  for (int j = 0; j < 4; j++)
    dst[(long)(c0 + ty + j * 8) * R + r0 + tx] = f2bf(tile[tx][ty + j * 8]);
}

// ---------------- bf16 GEMM: C[M,N] = A[M,K] * Bt[N,K]^T ----------------
// m97 recipe: 128x128x32 tiles, 4 waves each 64x64, global_load_lds width 16.
template <typename OutT>
__global__ __launch_bounds__(256) void gemm_bt(
    const ushort_t* __restrict__ A, const ushort_t* __restrict__ Bt,
    OutT* __restrict__ C, int M, int N, int K) {
  __shared__ __align__(16) ushort_t As[128 * 32];
  __shared__ __align__(16) ushort_t Bs[128 * 32];
  const int t = threadIdx.x;
  const int wave = t >> 6, lane = t & 63;
  const int wr = wave >> 1, wc = wave & 1;
  const int quad = lane >> 4, l16 = lane & 15;
  const long bm = (long)blockIdx.y * 128, bn = (long)blockIdx.x * 128;

  f32x4 acc[4][4] = {};

  const int srow = t >> 2, schunk = t & 3;
  const ushort_t* aSrc = A + (bm + srow) * (long)K + schunk * 8;
  const ushort_t* bSrc = Bt + (bn + srow) * (long)K + schunk * 8;
  const int ldsOff = srow * 32 + schunk * 8;

  for (int k0 = 0; k0 < K; k0 += 32) {
    __syncthreads();
    gload_lds16(aSrc + k0, &As[ldsOff]);
    gload_lds16(aSrc + (long)64 * K + k0, &As[ldsOff + 64 * 32]);
    gload_lds16(bSrc + k0, &Bs[ldsOff]);
    gload_lds16(bSrc + (long)64 * K + k0, &Bs[ldsOff + 64 * 32]);
    __syncthreads();
    short8 af[4], bf[4];
#pragma unroll
    for (int i = 0; i < 4; i++) {
      af[i] = *(const short8*)&As[(wr * 64 + i * 16 + l16) * 32 + quad * 8];
      bf[i] = *(const short8*)&Bs[(wc * 64 + i * 16 + l16) * 32 + quad * 8];
    }
#pragma unroll
    for (int i = 0; i < 4; i++)
#pragma unroll
      for (int j = 0; j < 4; j++)
        acc[i][j] = __builtin_amdgcn_mfma_f32_16x16x32_bf16(af[i], bf[j], acc[i][j], 0, 0, 0);
  }
#pragma unroll
  for (int i = 0; i < 4; i++)
#pragma unroll
    for (int j = 0; j < 4; j++)
#pragma unroll
      for (int r = 0; r < 4; r++) {
        long rr = bm + wr * 64 + i * 16 + quad * 4 + r;
        long cc = bn + wc * 64 + j * 16 + l16;
        store_out(&C[rr * N + cc], acc[i][j][r]);
      }
}

// ---------------- RMSNorm + RoPE, in place on bf16 qkv ----------------
__global__ __launch_bounds__(256) void rmsnorm_rope(
    ushort_t* __restrict__ qkv, const int* __restrict__ positions,
    const float* __restrict__ qw, const float* __restrict__ kw) {
  int gw = blockIdx.x * 4 + (threadIdx.x >> 6);
  int lane = threadIdx.x & 63;
  int bs = gw / 20, h = gw % 20;
  ushort_t* src = qkv + (long)bs * 3072 + h * 128;
  float x0 = bf2f(src[lane]), x1 = bf2f(src[lane + 64]);
  float ss = x0 * x0 + x1 * x1;
#pragma unroll
  for (int off = 32; off; off >>= 1) ss += __shfl_xor(ss, off);
  float r = rsqrtf(ss * (1.0f / 128.0f) + EPS_);
  const float* w = (h < 16) ? qw : kw;
  x0 = x0 * r * w[lane];
  x1 = x1 * r * w[lane + 64];
  float pos = (float)positions[bs];
  float inv_freq = powf(THETA_, -(float)lane * (1.0f / 64.0f));
  float f = pos * inv_freq;
  float sn, cs;
  sincosf(f, &sn, &cs);
  float o0 = x0 * cs - x1 * sn;
  float o1 = x1 * cs + x0 * sn;
  src[lane] = f2bf(o0);
  src[lane + 64] = f2bf(o1);
}

// ------ V transpose: qkv [B,S,3072] v-columns -> Vt [B,NKV,D,S] ------
__global__ __launch_bounds__(256) void transpose_v(
    const ushort_t* __restrict__ qkv, ushort_t* __restrict__ Vt) {
  __shared__ ushort_t tile[64][65];
  int bh = blockIdx.z; // b*NKV + hk
  int s0 = blockIdx.x * 64, d0 = blockIdx.y * 64;
  int b = bh >> 2, hk = bh & 3;
  int tx = threadIdx.x & 63, ty = threadIdx.x >> 6; // ty 0..3
#pragma unroll
  for (int j = 0; j < 16; j++) {
    int sl = j * 4 + ty;
    tile[sl][tx] = qkv[(long)(b * Ss + s0 + sl) * 3072 + 2560 + hk * 128 + d0 + tx];
  }
  __syncthreads();
  const long vtbase = (long)bh * Dd * Ss;
#pragma unroll
  for (int j = 0; j < 16; j++) {
    int dl = j * 4 + ty;
    Vt[vtbase + (long)(d0 + dl) * Ss + s0 + tx] = tile[tx][dl];
  }
}

// ---------------- flash attention (register-prefetch pipeline) ----------------
// grid (S/64, NH, B); 4 waves; wave w owns Q rows [qt*64+w*16, +16).
// K/V tile t+1 prefetched into VGPRs during compute of tile t; regs->LDS at
// top of each iteration (vmcnt wait hidden under the previous compute).
// LDS 40 KB -> 4 blocks/CU; launch_bounds(256,4) caps VGPR<=128.
__global__ __launch_bounds__(256, 4) void flash_attn(
    const ushort_t* __restrict__ qkv, const ushort_t* __restrict__ Vt,
    ushort_t* __restrict__ ctx) {
  __shared__ __align__(16) ushort_t Ks[64 * 128];   // [kvrow][d] (16 chunks/row)
  __shared__ __align__(16) ushort_t Vs[128 * 64];   // [d][kv]    (8 chunks/row)
  __shared__ __align__(16) ushort_t Ps[4][16 * 64]; // per-wave P (8 chunks/row)
  const int qt = blockIdx.x, h = blockIdx.y, b = blockIdx.z;
  const int hk = h >> 2;
  const int t = threadIdx.x, wave = t >> 6, lane = t & 63;
  const int quad = lane >> 4, l16 = lane & 15;

  const ushort_t* qp = qkv + (long)(b * Ss + qt * 64) * 3072 + h * 128;
  const ushort_t* kp = qkv + (long)(b * Ss) * 3072 + 2048 + hk * 128;
  const ushort_t* vp = Vt + ((long)(b * NKV + hk) * Dd) * Ss;

  // Q A-fragments straight to registers.
  short8 qf[4];
  {
    const ushort_t* qrow = qp + (long)(wave * 16 + l16) * 3072 + quad * 8;
#pragma unroll
    for (int kc = 0; kc < 4; kc++)
      qf[kc] = *(const short8*)(qrow + kc * 32);
  }

  // Per-thread staging slots (fixed): 4 K chunks + 4 V chunks of 16 B.
  const ushort_t* kga[4];
  const ushort_t* vga[4];
  int ldsoff[4];
#pragma unroll
  for (int it = 0; it < 4; it++) {
    int tt = t + it * 256;
    int rowk = tt >> 4, cgk = (tt & 15) ^ (rowk & 15);
    kga[it] = kp + (long)rowk * 3072 + cgk * 8;
    int rowv = tt >> 3, cgv = (tt & 7) ^ (rowv & 7);
    vga[it] = vp + (long)rowv * Ss + cgv * 8;
    ldsoff[it] = tt * 8;
  }

  // preload tile 0
  int4 kreg[4], vreg[4];
#pragma unroll
  for (int it = 0; it < 4; it++) {
    kreg[it] = *(const int4*)(kga[it]);
    vreg[it] = *(const int4*)(vga[it]);
  }

  float m_i[4] = {-1e30f, -1e30f, -1e30f, -1e30f};
  float l_i[4] = {0.f, 0.f, 0.f, 0.f};
  f32x4 o[8] = {};

  for (int kt = 0; kt < Ss / 64; kt++) {
    __syncthreads(); // prior iteration's LDS reads done
#pragma unroll
    for (int it = 0; it < 4; it++) {
      *(int4*)&Ks[ldsoff[it]] = kreg[it];
      *(int4*)&Vs[ldsoff[it]] = vreg[it];
    }
    // issue next tile's loads (branchless: last iter re-loads tile 31)
    {
      const int ktn = (kt < Ss / 64 - 1) ? kt + 1 : kt;
      const long koff = (long)ktn * 64 * 3072;
      const int voff = ktn * 64;
#pragma unroll
      for (int it = 0; it < 4; it++) {
        kreg[it] = *(const int4*)(kga[it] + koff);
        vreg[it] = *(const int4*)(vga[it] + voff);
      }
    }
    __syncthreads(); // LDS writes visible

    // S = Q K^T (16x64 per wave), raw units
    f32x4 sa[4] = {};
#pragma unroll
    for (int kc = 0; kc < 4; kc++) {
#pragma unroll
      for (int nt = 0; nt < 4; nt++) {
        int brow = nt * 16 + l16;
        short8 bfr = *(const short8*)&Ks[brow * 128 + (((kc * 4 + quad) ^ (brow & 15)) * 8)];
        sa[nt] = __builtin_amdgcn_mfma_f32_16x16x32_bf16(qf[kc], bfr, sa[nt], 0, 0, 0);
      }
    }

    // online softmax (raw-unit max; exp2 with folded scale)
    float mc[4], alpha[4];
#pragma unroll
    for (int r = 0; r < 4; r++) {
      float mx = fmaxf(fmaxf(sa[0][r], sa[1][r]), fmaxf(sa[2][r], sa[3][r]));
#pragma unroll
      for (int off = 8; off; off >>= 1) mx = fmaxf(mx, __shfl_xor(mx, off));
      float mnew = fmaxf(m_i[r], mx);
      alpha[r] = __builtin_amdgcn_exp2f((m_i[r] - mnew) * C2_);
      m_i[r] = mnew;
      mc[r] = mnew * C2_;
    }
    float rs[4] = {0.f, 0.f, 0.f, 0.f};
#pragma unroll
    for (int nt = 0; nt < 4; nt++)
#pragma unroll
      for (int r = 0; r < 4; r++) {
        float p = __builtin_amdgcn_exp2f(__builtin_fmaf(sa[nt][r], C2_, -mc[r]));
        sa[nt][r] = p;
        rs[r] += p;
      }
#pragma unroll
    for (int r = 0; r < 4; r++) {
#pragma unroll
      for (int off = 8; off; off >>= 1) rs[r] += __shfl_xor(rs[r], off);
      l_i[r] = l_i[r] * alpha[r] + rs[r];
    }
    // P -> LDS (bf16 round-half-up: p in [0,1]); wave-private
#pragma unroll
    for (int nt = 0; nt < 4; nt++)
#pragma unroll
      for (int r = 0; r < 4; r++) {
        int row = quad * 4 + r, col = nt * 16 + l16;
        int cg = col >> 3, ci = col & 7;
        int cl = cg ^ (row & 7);
        union { float f; unsigned u; } pv; pv.f = sa[nt][r];
        Ps[wave][row * 64 + cl * 8 + ci] = (ushort_t)((pv.u + 0x8000u) >> 16);
      }
    // rescale O while the P stores drain (independent VALU work)
#pragma unroll
    for (int dt = 0; dt < 8; dt++)
#pragma unroll
      for (int r = 0; r < 4; r++) o[dt][r] *= alpha[r];
    asm volatile("s_waitcnt lgkmcnt(0)" ::: "memory");
    // O += P V
#pragma unroll
    for (int kc = 0; kc < 2; kc++) {
      int arow = l16;
      short8 af = *(const short8*)&Ps[wave][arow * 64 + (((kc * 4 + quad) ^ (arow & 7)) * 8)];
#pragma unroll
      for (int dt = 0; dt < 8; dt++) {
        int brow = dt * 16 + l16;
        short8 bfr = *(const short8*)&Vs[brow * 64 + (((kc * 4 + quad) ^ (brow & 7)) * 8)];
        o[dt] = __builtin_amdgcn_mfma_f32_16x16x32_bf16(af, bfr, o[dt], 0, 0, 0);
      }
    }
  }
  // epilogue: O /= l, write ctx [B*S, NH*D]
  const long obase = (long)(b * Ss + qt * 64 + wave * 16) * (NH * Dd) + h * Dd;
#pragma unroll
  for (int dt = 0; dt < 8; dt++)
#pragma unroll
    for (int r = 0; r < 4; r++) {
      int row = quad * 4 + r, col = dt * 16 + l16;
      ctx[obase + (long)row * (NH * Dd) + col] = f2bf(o[dt][r] / l_i[r]);
    }
}

extern "C" void kernel_launch(void* const* d_in, const int* in_sizes, int n_in,
                              void* d_out, int out_size, void* d_ws, size_t ws_size,
                              hipStream_t stream) {
  const float* hidden = (const float*)d_in[0];
  const int* positions = (const int*)d_in[1];
  const float* Wq = (const float*)d_in[2];
  const float* Wk = (const float*)d_in[3];
  const float* Wv = (const float*)d_in[4];
  const float* Wo = (const float*)d_in[5];
  const float* qw = (const float*)d_in[6];
  const float* kw = (const float*)d_in[7];
  float* out = (float*)d_out;

  // 64 MB workspace layout:
  char* ws = (char*)d_ws;
  ushort_t* Xbf = (ushort_t*)(ws);                    // 16 MB (4096x2048 bf16)
  ushort_t* WqkvT = (ushort_t*)(ws + (16l << 20));    // 12 MB (3072x2048 bf16)
  ushort_t* WoT = (ushort_t*)(ws + (28l << 20));      //  8 MB (2048x2048 bf16)
  ushort_t* qkvb = (ushort_t*)(ws + (36l << 20));     // 24 MB (4096x3072 bf16)
  ushort_t* Vt = (ushort_t*)(ws + (60l << 20));       //  4 MB (B,NKV,D,S bf16)
  ushort_t* ctx = Xbf;                                // reuse (dead after GEMM1)

  const long nX = (long)Bb * Ss * HID;
  convert_f32_bf16<<<(unsigned)(nX / 4 / 256), 256, 0, stream>>>(hidden, Xbf, nX);
  transpose_f32_bf16<<<dim3(2048 / 32, 2048 / 32), 256, 0, stream>>>(Wq, WqkvT, 2048, 2048);
  transpose_f32_bf16<<<dim3(512 / 32, 2048 / 32), 256, 0, stream>>>(Wk, WqkvT + (long)2048 * 2048, 2048, 512);
  transpose_f32_bf16<<<dim3(512 / 32, 2048 / 32), 256, 0, stream>>>(Wv, WqkvT + (long)2560 * 2048, 2048, 512);
  transpose_f32_bf16<<<dim3(2048 / 32, 2048 / 32), 256, 0, stream>>>(Wo, WoT, 2048, 2048);

  gemm_bt<ushort_t><<<dim3(3072 / 128, 4096 / 128), 256, 0, stream>>>(Xbf, WqkvT, qkvb, 4096, 3072, 2048);

  rmsnorm_rope<<<(Bb * Ss * 20) / 4, 256, 0, stream>>>(qkvb, positions, qw, kw);
  transpose_v<<<dim3(Ss / 64, Dd / 64, Bb * NKV), 256, 0, stream>>>(qkvb, Vt);

  flash_attn<<<dim3(Ss / 64, NH, Bb), 256, 0, stream>>>(qkvb, Vt, ctx);

  gemm_bt<float><<<dim3(2048 / 128, 4096 / 128), 256, 0, stream>>>(ctx, WoT, out, 4096, 2048, 2048);
}

// Round 7
// 400.457 us; speedup vs baseline: 1.6642x; 1.6642x over previous
//
#include <hip/hip_runtime.h>

typedef unsigned short ushort_t;
typedef __attribute__((ext_vector_type(8))) short short8;
typedef __attribute__((ext_vector_type(4))) float f32x4;

#define Bb 2
#define Ss 2048
#define HID 2048
#define NH 16
#define NKV 4
#define Dd 128
constexpr float EPS_ = 1e-6f;
constexpr float THETA_ = 1000000.0f;
constexpr float SCALE_ = 0.08838834764831845f; // 128^-0.5
constexpr float C2_ = 0.12753785f;             // SCALE * log2(e)

__device__ __forceinline__ ushort_t f2bf(float x) {
  union { float f; unsigned u; } v; v.f = x;
  unsigned r = (v.u + 0x7fffu + ((v.u >> 16) & 1u)) >> 16;
  return (ushort_t)r;
}
__device__ __forceinline__ float bf2f(ushort_t u) {
  union { unsigned u; float f; } v; v.u = ((unsigned)u) << 16;
  return v.f;
}

typedef const __attribute__((address_space(1))) void* gas1_t;
typedef __attribute__((address_space(3))) void* las3_t;
__device__ __forceinline__ void gload_lds16(const void* g, void* l) {
  __builtin_amdgcn_global_load_lds((gas1_t)g, (las3_t)l, 16, 0, 0);
}

__device__ __forceinline__ void store_out(float* p, float v) { *p = v; }
__device__ __forceinline__ void store_out(ushort_t* p, float v) { *p = f2bf(v); }

// ---------------- fp32 -> bf16 straight convert ----------------
__global__ __launch_bounds__(256) void convert_f32_bf16(
    const float* __restrict__ src, ushort_t* __restrict__ dst, long n) {
  long i = ((long)blockIdx.x * 256 + threadIdx.x) * 4;
  if (i + 3 < n) {
    float4 v = *(const float4*)(src + i);
    ushort_t o0 = f2bf(v.x), o1 = f2bf(v.y), o2 = f2bf(v.z), o3 = f2bf(v.w);
    ushort_t* d = dst + i;
    d[0] = o0; d[1] = o1; d[2] = o2; d[3] = o3;
  }
}

// ---------------- fp32 (R x C) -> bf16 transposed (C x R) ----------------
__global__ __launch_bounds__(256) void transpose_f32_bf16(
    const float* __restrict__ src, ushort_t* __restrict__ dst, int R, int C) {
  __shared__ float tile[32][33];
  int c0 = blockIdx.x * 32, r0 = blockIdx.y * 32;
  int tx = threadIdx.x & 31, ty = threadIdx.x >> 5; // ty 0..7
#pragma unroll
  for (int j = 0; j < 4; j++)
    tile[ty + j * 8][tx] = src[(long)(r0 + ty + j * 8) * C + c0 + tx];
  __syncthreads();
#pragma unroll
  for (int j = 0; j < 4; j++)
    dst[(long)(c0 + ty + j * 8) * R + r0 + tx] = f2bf(tile[tx][ty + j * 8]);
}

// ---------------- bf16 GEMM: C[M,N] = A[M,K] * Bt[N,K]^T ----------------
// m97 recipe: 128x128x32 tiles, 4 waves each 64x64, global_load_lds width 16.
template <typename OutT>
__global__ __launch_bounds__(256) void gemm_bt(
    const ushort_t* __restrict__ A, const ushort_t* __restrict__ Bt,
    OutT* __restrict__ C, int M, int N, int K) {
  __shared__ __align__(16) ushort_t As[128 * 32];
  __shared__ __align__(16) ushort_t Bs[128 * 32];
  const int t = threadIdx.x;
  const int wave = t >> 6, lane = t & 63;
  const int wr = wave >> 1, wc = wave & 1;
  const int quad = lane >> 4, l16 = lane & 15;
  const long bm = (long)blockIdx.y * 128, bn = (long)blockIdx.x * 128;

  f32x4 acc[4][4] = {};

  const int srow = t >> 2, schunk = t & 3;
  const ushort_t* aSrc = A + (bm + srow) * (long)K + schunk * 8;
  const ushort_t* bSrc = Bt + (bn + srow) * (long)K + schunk * 8;
  const int ldsOff = srow * 32 + schunk * 8;

  for (int k0 = 0; k0 < K; k0 += 32) {
    __syncthreads();
    gload_lds16(aSrc + k0, &As[ldsOff]);
    gload_lds16(aSrc + (long)64 * K + k0, &As[ldsOff + 64 * 32]);
    gload_lds16(bSrc + k0, &Bs[ldsOff]);
    gload_lds16(bSrc + (long)64 * K + k0, &Bs[ldsOff + 64 * 32]);
    __syncthreads();
    short8 af[4], bf[4];
#pragma unroll
    for (int i = 0; i < 4; i++) {
      af[i] = *(const short8*)&As[(wr * 64 + i * 16 + l16) * 32 + quad * 8];
      bf[i] = *(const short8*)&Bs[(wc * 64 + i * 16 + l16) * 32 + quad * 8];
    }
#pragma unroll
    for (int i = 0; i < 4; i++)
#pragma unroll
      for (int j = 0; j < 4; j++)
        acc[i][j] = __builtin_amdgcn_mfma_f32_16x16x32_bf16(af[i], bf[j], acc[i][j], 0, 0, 0);
  }
#pragma unroll
  for (int i = 0; i < 4; i++)
#pragma unroll
    for (int j = 0; j < 4; j++)
#pragma unroll
      for (int r = 0; r < 4; r++) {
        long rr = bm + wr * 64 + i * 16 + quad * 4 + r;
        long cc = bn + wc * 64 + j * 16 + l16;
        store_out(&C[rr * N + cc], acc[i][j][r]);
      }
}

// ---------------- RMSNorm + RoPE, in place on bf16 qkv ----------------
__global__ __launch_bounds__(256) void rmsnorm_rope(
    ushort_t* __restrict__ qkv, const int* __restrict__ positions,
    const float* __restrict__ qw, const float* __restrict__ kw) {
  int gw = blockIdx.x * 4 + (threadIdx.x >> 6);
  int lane = threadIdx.x & 63;
  int bs = gw / 20, h = gw % 20;
  ushort_t* src = qkv + (long)bs * 3072 + h * 128;
  float x0 = bf2f(src[lane]), x1 = bf2f(src[lane + 64]);
  float ss = x0 * x0 + x1 * x1;
#pragma unroll
  for (int off = 32; off; off >>= 1) ss += __shfl_xor(ss, off);
  float r = rsqrtf(ss * (1.0f / 128.0f) + EPS_);
  const float* w = (h < 16) ? qw : kw;
  x0 = x0 * r * w[lane];
  x1 = x1 * r * w[lane + 64];
  float pos = (float)positions[bs];
  float inv_freq = powf(THETA_, -(float)lane * (1.0f / 64.0f));
  float f = pos * inv_freq;
  float sn, cs;
  sincosf(f, &sn, &cs);
  float o0 = x0 * cs - x1 * sn;
  float o1 = x1 * cs + x0 * sn;
  src[lane] = f2bf(o0);
  src[lane + 64] = f2bf(o1);
}

// ------ V transpose: qkv [B,S,3072] v-columns -> Vt [B,NKV,D,S] ------
__global__ __launch_bounds__(256) void transpose_v(
    const ushort_t* __restrict__ qkv, ushort_t* __restrict__ Vt) {
  __shared__ ushort_t tile[64][65];
  int bh = blockIdx.z; // b*NKV + hk
  int s0 = blockIdx.x * 64, d0 = blockIdx.y * 64;
  int b = bh >> 2, hk = bh & 3;
  int tx = threadIdx.x & 63, ty = threadIdx.x >> 6; // ty 0..3
#pragma unroll
  for (int j = 0; j < 16; j++) {
    int sl = j * 4 + ty;
    tile[sl][tx] = qkv[(long)(b * Ss + s0 + sl) * 3072 + 2560 + hk * 128 + d0 + tx];
  }
  __syncthreads();
  const long vtbase = (long)bh * Dd * Ss;
#pragma unroll
  for (int j = 0; j < 16; j++) {
    int dl = j * 4 + ty;
    Vt[vtbase + (long)(d0 + dl) * Ss + s0 + tx] = tile[tx][dl];
  }
}

// ---------------- flash attention ----------------
// grid (S/128, NH, B); 512 threads = 8 waves; wave w owns Q rows
// [qt*128 + w*16, +16). One staged 64-key K/V tile feeds all 8 waves
// (2x the MFMA per staged byte vs the 4-wave version). Per-wave code
// identical to the r5 kernel (64 VGPRs, no arrays -> no spill).
// LDS 48 KB -> 3 blocks/CU capacity; 512 blocks -> 2 resident.
__global__ __launch_bounds__(512) void flash_attn(
    const ushort_t* __restrict__ qkv, const ushort_t* __restrict__ Vt,
    ushort_t* __restrict__ ctx) {
  __shared__ __align__(16) ushort_t Ks[64 * 128];   // [kvrow][d] (16 chunks/row)
  __shared__ __align__(16) ushort_t Vs[128 * 64];   // [d][kv]    (8 chunks/row)
  __shared__ __align__(16) ushort_t Ps[8][16 * 64]; // per-wave P (8 chunks/row)
  const int qt = blockIdx.x, h = blockIdx.y, b = blockIdx.z;
  const int hk = h >> 2;
  const int t = threadIdx.x, wave = t >> 6, lane = t & 63;
  const int quad = lane >> 4, l16 = lane & 15;

  const ushort_t* qp = qkv + (long)(b * Ss + qt * 128) * 3072 + h * 128;
  const ushort_t* kp = qkv + (long)(b * Ss) * 3072 + 2048 + hk * 128;
  const ushort_t* vp = Vt + ((long)(b * NKV + hk) * Dd) * Ss;

  // Q A-fragments straight to registers.
  short8 qf[4];
  {
    const ushort_t* qrow = qp + (long)(wave * 16 + l16) * 3072 + quad * 8;
#pragma unroll
    for (int kc = 0; kc < 4; kc++)
      qf[kc] = *(const short8*)(qrow + kc * 32);
  }

  float m_i[4] = {-1e30f, -1e30f, -1e30f, -1e30f};
  float l_i[4] = {0.f, 0.f, 0.f, 0.f};
  f32x4 o[8] = {};

  for (int kt = 0; kt < Ss / 64; kt++) {
    const int k0 = kt * 64;
    __syncthreads(); // prior iteration's LDS reads done
#pragma unroll
    for (int it = 0; it < 2; it++) {
      int tt = t + it * 512;
      int row = tt >> 4, cl = tt & 15, cg = cl ^ (row & 15);
      gload_lds16(kp + (long)(k0 + row) * 3072 + cg * 8, &Ks[tt * 8]);
    }
#pragma unroll
    for (int it = 0; it < 2; it++) {
      int tt = t + it * 512;
      int row = tt >> 3, cl = tt & 7, cg = cl ^ (row & 7);
      gload_lds16(vp + (long)row * Ss + k0 + cg * 8, &Vs[tt * 8]);
    }
    __syncthreads();

    // S = Q K^T (16x64 per wave), raw units
    f32x4 sa[4] = {};
#pragma unroll
    for (int kc = 0; kc < 4; kc++) {
#pragma unroll
      for (int nt = 0; nt < 4; nt++) {
        int brow = nt * 16 + l16;
        short8 bfr = *(const short8*)&Ks[brow * 128 + (((kc * 4 + quad) ^ (brow & 15)) * 8)];
        sa[nt] = __builtin_amdgcn_mfma_f32_16x16x32_bf16(qf[kc], bfr, sa[nt], 0, 0, 0);
      }
    }

    // online softmax (raw-unit max; exp2 with folded scale)
    float mc[4], alpha[4];
#pragma unroll
    for (int r = 0; r < 4; r++) {
      float mx = fmaxf(fmaxf(sa[0][r], sa[1][r]), fmaxf(sa[2][r], sa[3][r]));
#pragma unroll
      for (int off = 8; off; off >>= 1) mx = fmaxf(mx, __shfl_xor(mx, off));
      float mnew = fmaxf(m_i[r], mx);
      alpha[r] = __builtin_amdgcn_exp2f((m_i[r] - mnew) * C2_);
      m_i[r] = mnew;
      mc[r] = mnew * C2_;
    }
    float rs[4] = {0.f, 0.f, 0.f, 0.f};
#pragma unroll
    for (int nt = 0; nt < 4; nt++)
#pragma unroll
      for (int r = 0; r < 4; r++) {
        float p = __builtin_amdgcn_exp2f(__builtin_fmaf(sa[nt][r], C2_, -mc[r]));
        sa[nt][r] = p;
        rs[r] += p;
      }
#pragma unroll
    for (int r = 0; r < 4; r++) {
#pragma unroll
      for (int off = 8; off; off >>= 1) rs[r] += __shfl_xor(rs[r], off);
      l_i[r] = l_i[r] * alpha[r] + rs[r];
    }
    // P -> LDS (bf16 round-half-up: p in [0,1]); wave-private
#pragma unroll
    for (int nt = 0; nt < 4; nt++)
#pragma unroll
      for (int r = 0; r < 4; r++) {
        int row = quad * 4 + r, col = nt * 16 + l16;
        int cg = col >> 3, ci = col & 7;
        int cl = cg ^ (row & 7);
        union { float f; unsigned u; } pv; pv.f = sa[nt][r];
        Ps[wave][row * 64 + cl * 8 + ci] = (ushort_t)((pv.u + 0x8000u) >> 16);
      }
    // rescale O while the P stores drain (independent VALU work)
#pragma unroll
    for (int dt = 0; dt < 8; dt++)
#pragma unroll
      for (int r = 0; r < 4; r++) o[dt][r] *= alpha[r];
    asm volatile("s_waitcnt lgkmcnt(0)" ::: "memory");
    // O += P V
#pragma unroll
    for (int kc = 0; kc < 2; kc++) {
      int arow = l16;
      short8 af = *(const short8*)&Ps[wave][arow * 64 + (((kc * 4 + quad) ^ (arow & 7)) * 8)];
#pragma unroll
      for (int dt = 0; dt < 8; dt++) {
        int brow = dt * 16 + l16;
        short8 bfr = *(const short8*)&Vs[brow * 64 + (((kc * 4 + quad) ^ (brow & 7)) * 8)];
        o[dt] = __builtin_amdgcn_mfma_f32_16x16x32_bf16(af, bfr, o[dt], 0, 0, 0);
      }
    }
  }
  // epilogue: O /= l, write ctx [B*S, NH*D]
  const long obase = (long)(b * Ss + qt * 128 + wave * 16) * (NH * Dd) + h * Dd;
#pragma unroll
  for (int dt = 0; dt < 8; dt++)
#pragma unroll
    for (int r = 0; r < 4; r++) {
      int row = quad * 4 + r, col = dt * 16 + l16;
      ctx[obase + (long)row * (NH * Dd) + col] = f2bf(o[dt][r] / l_i[r]);
    }
}

extern "C" void kernel_launch(void* const* d_in, const int* in_sizes, int n_in,
                              void* d_out, int out_size, void* d_ws, size_t ws_size,
                              hipStream_t stream) {
  const float* hidden = (const float*)d_in[0];
  const int* positions = (const int*)d_in[1];
  const float* Wq = (const float*)d_in[2];
  const float* Wk = (const float*)d_in[3];
  const float* Wv = (const float*)d_in[4];
  const float* Wo = (const float*)d_in[5];
  const float* qw = (const float*)d_in[6];
  const float* kw = (const float*)d_in[7];
  float* out = (float*)d_out;

  // 64 MB workspace layout:
  char* ws = (char*)d_ws;
  ushort_t* Xbf = (ushort_t*)(ws);                    // 16 MB (4096x2048 bf16)
  ushort_t* WqkvT = (ushort_t*)(ws + (16l << 20));    // 12 MB (3072x2048 bf16)
  ushort_t* WoT = (ushort_t*)(ws + (28l << 20));      //  8 MB (2048x2048 bf16)
  ushort_t* qkvb = (ushort_t*)(ws + (36l << 20));     // 24 MB (4096x3072 bf16)
  ushort_t* Vt = (ushort_t*)(ws + (60l << 20));       //  4 MB (B,NKV,D,S bf16)
  ushort_t* ctx = Xbf;                                // reuse (dead after GEMM1)

  const long nX = (long)Bb * Ss * HID;
  convert_f32_bf16<<<(unsigned)(nX / 4 / 256), 256, 0, stream>>>(hidden, Xbf, nX);
  transpose_f32_bf16<<<dim3(2048 / 32, 2048 / 32), 256, 0, stream>>>(Wq, WqkvT, 2048, 2048);
  transpose_f32_bf16<<<dim3(512 / 32, 2048 / 32), 256, 0, stream>>>(Wk, WqkvT + (long)2048 * 2048, 2048, 512);
  transpose_f32_bf16<<<dim3(512 / 32, 2048 / 32), 256, 0, stream>>>(Wv, WqkvT + (long)2560 * 2048, 2048, 512);
  transpose_f32_bf16<<<dim3(2048 / 32, 2048 / 32), 256, 0, stream>>>(Wo, WoT, 2048, 2048);

  gemm_bt<ushort_t><<<dim3(3072 / 128, 4096 / 128), 256, 0, stream>>>(Xbf, WqkvT, qkvb, 4096, 3072, 2048);

  rmsnorm_rope<<<(Bb * Ss * 20) / 4, 256, 0, stream>>>(qkvb, positions, qw, kw);
  transpose_v<<<dim3(Ss / 64, Dd / 64, Bb * NKV), 256, 0, stream>>>(qkvb, Vt);

  flash_attn<<<dim3(Ss / 128, NH, Bb), 512, 0, stream>>>(qkvb, Vt, ctx);

  gemm_bt<float><<<dim3(2048 / 128, 4096 / 128), 256, 0, stream>>>(ctx, WoT, out, 4096, 2048, 2048);
}